// Round 1
// baseline (11655.584 us; speedup 1.0000x reference)
//
#include <hip/hip_runtime.h>
#include <hip/hip_bf16.h>

// Model: BiLSTM encoder (L=400) + coverage-attention LSTM decoder (99 steps) + V=50000 softmax.
// B=16, E=128, H=256, 4H=1024, 2H=512, 3H=768.
//
// Key restructurings (all exact algebra, reassociation only):
//  - input projections x@Wih.T batched up front (gather-GEMM from embed)
//  - attention logits collapsed: logit[b][l] = vWh[b*L+l] + vswc[(b*L+l)%16] + c0
//    (faithful to the reference's .repeat() batch-minor tiling bug)
//  - (cat@V1.T)@V2.T hoisted out of the decoder loop into one [1584,50000] bf16 MFMA GEMM
//
// ws layout (float units), ~84.5 MB total; V2_w bf16 copy aliases the Xf..cat region
// (dead by conversion time).

#define BB 16
#define LL 400
#define TD 99
#define EE 128
#define HH 256
#define G4 1024
#define H2 512
#define H3 768
#define VV 50000

typedef __attribute__((ext_vector_type(8))) short bf16x8_t;
typedef __attribute__((ext_vector_type(4))) float f32x4_t;

static constexpr size_t OFF_XF   = 0;                          // 400*16*1024
static constexpr size_t OFF_XB   = OFF_XF + 6553600;
static constexpr size_t OFF_XD   = OFF_XB + 6553600;           // 99*16*1024
static constexpr size_t OFF_ENC  = OFF_XD + 1622016;           // 16*400*512
static constexpr size_t OFF_CAT  = OFF_ENC + 3276800;          // 1584*768
static constexpr size_t OFF_ZALL = OFF_CAT + 1216512;          // 1584*768
static constexpr size_t OFF_ZBF  = OFF_ZALL + 1216512;         // 1584*768 bf16 = 608256 float slots
static constexpr size_t OFF_VWH  = OFF_ZBF + 608256;           // 6400
static constexpr size_t OFF_VWS  = OFF_VWH + 6400;             // 256
static constexpr size_t OFF_VWC  = OFF_VWS + 256;              // 400
static constexpr size_t OFF_VWHW = OFF_VWC + 400;              // 512
static constexpr size_t OFF_C0   = OFF_VWHW + 512;             // 16
static constexpr size_t OFF_STATE= OFF_C0 + 16;                // zero region start
static constexpr size_t OFF_HF0  = OFF_STATE;
static constexpr size_t OFF_HF1  = OFF_HF0 + 4096;
static constexpr size_t OFF_HB0  = OFF_HF1 + 4096;
static constexpr size_t OFF_HB1  = OFF_HB0 + 4096;
static constexpr size_t OFF_HD0  = OFF_HB1 + 4096;
static constexpr size_t OFF_HD1  = OFF_HD0 + 4096;
static constexpr size_t OFF_CF   = OFF_HD1 + 4096;
static constexpr size_t OFF_CB   = OFF_CF + 4096;
static constexpr size_t OFF_CD   = OFF_CB + 4096;
static constexpr size_t OFF_COVA = OFF_CD + 4096;              // 6400
static constexpr size_t OFF_COVB = OFF_COVA + 6400;            // 6400
static constexpr size_t OFF_CVL  = OFF_COVB + 6400;            // 16
static constexpr size_t ZERO_N   = (OFF_CVL + 16) - OFF_STATE; // 49680
static constexpr size_t OFF_ATTN = OFF_CVL + 16;               // 6400
static constexpr size_t OFF_V2BF = 0;  // 38.4M bf16 = 19.2M float slots, < OFF_ZALL: aliases dead Xf..cat

// ---------------- init: zero state region ----------------
__global__ void k_init(float* __restrict__ p, int n) {
    for (int i = blockIdx.x * blockDim.x + threadIdx.x; i < n; i += gridDim.x * blockDim.x)
        p[i] = 0.0f;
}

// ---------------- precompute v-folded attention vectors ----------------
__global__ void k_precomp(const float* __restrict__ v, const float* __restrict__ Ws_w,
                          const float* __restrict__ Wc_w, const float* __restrict__ Wh_w,
                          const float* __restrict__ Wh_b, const float* __restrict__ Ws_b,
                          const float* __restrict__ Wc_b, const float* __restrict__ v_b,
                          float* __restrict__ vWs, float* __restrict__ vWc,
                          float* __restrict__ vWhw, float* __restrict__ c0) {
    int tid = threadIdx.x;
    {
        float a = 0.f;
        for (int j = 0; j < 256; ++j) a += v[j] * Ws_w[j * 256 + tid];
        vWs[tid] = a;
    }
    for (int k = tid; k < 400; k += 256) {
        float a = 0.f;
        for (int j = 0; j < 256; ++j) a += v[j] * Wc_w[j * 400 + k];
        vWc[k] = a;
    }
    for (int k = tid; k < 512; k += 256) {
        float a = 0.f;
        for (int j = 0; j < 256; ++j) a += v[j] * Wh_w[j * 512 + k];
        vWhw[k] = a;
    }
    if (tid == 0) {
        float a = 0.f;
        for (int j = 0; j < 256; ++j) a += v[j] * (Wh_b[j] + Ws_b[j] + Wc_b[j]);
        c0[0] = a + v_b[0];
    }
}

// ---------------- generic fp32 GEMM: C[M,N] = A@B.T + bias, optional A-gather ----------------
// If idx != nullptr: A row r = embed[idx[(r&15)*idxS + (r>>4)]] (row length K).
__global__ __launch_bounds__(256) void k_gemm_f32(
    const float* __restrict__ A, const float* __restrict__ emb, const int* __restrict__ idx,
    int idxS, const float* __restrict__ Bm, const float* __restrict__ bias,
    float* __restrict__ C, int M, int N, int K) {
    __shared__ float As[16][68];
    __shared__ float Bs[16][68];
    int tid = threadIdx.x;
    int m0 = blockIdx.y * 64, n0 = blockIdx.x * 64;
    int lrow = tid >> 2;
    int lk = (tid & 3) << 2;
    int ty = tid >> 4, tx = tid & 15;
    float acc[4][4] = {};
    for (int k0 = 0; k0 < K; k0 += 16) {
        float4 av = {0.f, 0.f, 0.f, 0.f}, bv = {0.f, 0.f, 0.f, 0.f};
        int mr = m0 + lrow;
        if (mr < M) {
            const float* src;
            if (idx) {
                int tok = idx[(mr & 15) * idxS + (mr >> 4)];
                src = emb + (size_t)tok * K;
            } else {
                src = A + (size_t)mr * K;
            }
            av = *(const float4*)(src + k0 + lk);
        }
        int nr = n0 + lrow;
        if (nr < N) bv = *(const float4*)(Bm + (size_t)nr * K + k0 + lk);
        __syncthreads();
        As[lk + 0][lrow] = av.x; As[lk + 1][lrow] = av.y;
        As[lk + 2][lrow] = av.z; As[lk + 3][lrow] = av.w;
        Bs[lk + 0][lrow] = bv.x; Bs[lk + 1][lrow] = bv.y;
        Bs[lk + 2][lrow] = bv.z; Bs[lk + 3][lrow] = bv.w;
        __syncthreads();
#pragma unroll
        for (int kk = 0; kk < 16; ++kk) {
            float4 a4 = *(const float4*)&As[kk][ty << 2];
            float4 b4 = *(const float4*)&Bs[kk][tx << 2];
            float ar[4] = {a4.x, a4.y, a4.z, a4.w};
            float br[4] = {b4.x, b4.y, b4.z, b4.w};
#pragma unroll
            for (int i = 0; i < 4; ++i)
#pragma unroll
                for (int j = 0; j < 4; ++j) acc[i][j] += ar[i] * br[j];
        }
    }
#pragma unroll
    for (int i = 0; i < 4; ++i) {
        int m = m0 + (ty << 2) + i;
        if (m >= M) continue;
#pragma unroll
        for (int j = 0; j < 4; ++j) {
            int n = n0 + (tx << 2) + j;
            if (n < N) C[(size_t)m * N + n] = acc[i][j] + (bias ? bias[n] : 0.f);
        }
    }
}

// ---------------- one encoder timestep, both directions (32 WGs) ----------------
// WG (dir, w): k-slice of 16; thread (b = tid&15, r = tid>>4) owns all 4 gates of (b, k=16w+r).
__global__ __launch_bounds__(256) void k_enc_step(
    const float* __restrict__ Xf, const float* __restrict__ Xb,
    const float* __restrict__ Whh_f, const float* __restrict__ Whh_b,
    const float* __restrict__ hin_f, const float* __restrict__ hin_b,
    float* __restrict__ hout_f, float* __restrict__ hout_b,
    float* __restrict__ c_f, float* __restrict__ c_b, float* __restrict__ enc, int t) {
    __shared__ float hs[16 * 260];
    int bx = blockIdx.x;
    int dir = bx >> 4, w = bx & 15;
    const float* Whh = dir ? Whh_b : Whh_f;
    const float* hin = dir ? hin_b : hin_f;
    float* hout = dir ? hout_b : hout_f;
    float* cbuf = dir ? c_b : c_f;
    int l = dir ? (LL - 1 - t) : t;
    const float* X = (dir ? Xb : Xf) + (size_t)l * (16 * G4);
    int tid = threadIdx.x;
    for (int i = tid; i < 4096; i += 256) {
        int bb = i >> 8, j = i & 255;
        hs[bb * 260 + j] = hin[i];
    }
    __syncthreads();
    int b = tid & 15, r = tid >> 4;
    int k = (w << 4) + r;
    const float* w0 = Whh + (size_t)(0 * 256 + k) * 256;
    const float* w1 = Whh + (size_t)(1 * 256 + k) * 256;
    const float* w2 = Whh + (size_t)(2 * 256 + k) * 256;
    const float* w3 = Whh + (size_t)(3 * 256 + k) * 256;
    const float* hrow = hs + b * 260;
    float g0 = 0.f, g1 = 0.f, g2 = 0.f, g3 = 0.f;
#pragma unroll 4
    for (int j = 0; j < 256; j += 4) {
        float4 hv = *(const float4*)(hrow + j);
        float4 a0 = *(const float4*)(w0 + j);
        float4 a1 = *(const float4*)(w1 + j);
        float4 a2 = *(const float4*)(w2 + j);
        float4 a3 = *(const float4*)(w3 + j);
        g0 += a0.x * hv.x + a0.y * hv.y + a0.z * hv.z + a0.w * hv.w;
        g1 += a1.x * hv.x + a1.y * hv.y + a1.z * hv.z + a1.w * hv.w;
        g2 += a2.x * hv.x + a2.y * hv.y + a2.z * hv.z + a2.w * hv.w;
        g3 += a3.x * hv.x + a3.y * hv.y + a3.z * hv.z + a3.w * hv.w;
    }
    g0 += X[b * G4 + k];
    g1 += X[b * G4 + 256 + k];
    g2 += X[b * G4 + 512 + k];
    g3 += X[b * G4 + 768 + k];
    float si = 1.f / (1.f + expf(-g0));
    float sf = 1.f / (1.f + expf(-g1));
    float tg = tanhf(g2);
    float so = 1.f / (1.f + expf(-g3));
    float c = sf * cbuf[b * 256 + k] + si * tg;
    cbuf[b * 256 + k] = c;
    float h = so * tanhf(c);
    hout[b * 256 + k] = h;
    enc[((size_t)b * LL + l) * H2 + dir * 256 + k] = h;
}

// ---------------- vWh[b*L+l] = vWhw . enc[b,l,:] ----------------
__global__ void k_vwh(const float* __restrict__ enc, const float* __restrict__ vWhw,
                      float* __restrict__ vWh) {
    int rr = blockIdx.x * 256 + threadIdx.x;  // < 6400
    const float* row = enc + (size_t)rr * H2;
    float acc = 0.f;
#pragma unroll 4
    for (int k = 0; k < H2; k += 4) {
        float4 e = *(const float4*)(row + k);
        float4 wv = *(const float4*)(vWhw + k);
        acc += e.x * wv.x + e.y * wv.y + e.z * wv.z + e.w * wv.w;
    }
    vWh[rr] = acc;
}

// ---------------- one decoder LSTM step (16 WGs); also writes h into cat_all ----------------
__global__ __launch_bounds__(256) void k_dec_step(
    const float* __restrict__ Xd, const float* __restrict__ Whh,
    const float* __restrict__ hin, float* __restrict__ hout, float* __restrict__ cbuf,
    float* __restrict__ cat, int t) {
    __shared__ float hs[16 * 260];
    int w = blockIdx.x;
    const float* X = Xd + (size_t)t * (16 * G4);
    int tid = threadIdx.x;
    for (int i = tid; i < 4096; i += 256) {
        int bb = i >> 8, j = i & 255;
        hs[bb * 260 + j] = hin[i];
    }
    __syncthreads();
    int b = tid & 15, r = tid >> 4;
    int k = (w << 4) + r;
    const float* w0 = Whh + (size_t)(0 * 256 + k) * 256;
    const float* w1 = Whh + (size_t)(1 * 256 + k) * 256;
    const float* w2 = Whh + (size_t)(2 * 256 + k) * 256;
    const float* w3 = Whh + (size_t)(3 * 256 + k) * 256;
    const float* hrow = hs + b * 260;
    float g0 = 0.f, g1 = 0.f, g2 = 0.f, g3 = 0.f;
#pragma unroll 4
    for (int j = 0; j < 256; j += 4) {
        float4 hv = *(const float4*)(hrow + j);
        float4 a0 = *(const float4*)(w0 + j);
        float4 a1 = *(const float4*)(w1 + j);
        float4 a2 = *(const float4*)(w2 + j);
        float4 a3 = *(const float4*)(w3 + j);
        g0 += a0.x * hv.x + a0.y * hv.y + a0.z * hv.z + a0.w * hv.w;
        g1 += a1.x * hv.x + a1.y * hv.y + a1.z * hv.z + a1.w * hv.w;
        g2 += a2.x * hv.x + a2.y * hv.y + a2.z * hv.z + a2.w * hv.w;
        g3 += a3.x * hv.x + a3.y * hv.y + a3.z * hv.z + a3.w * hv.w;
    }
    g0 += X[b * G4 + k];
    g1 += X[b * G4 + 256 + k];
    g2 += X[b * G4 + 512 + k];
    g3 += X[b * G4 + 768 + k];
    float si = 1.f / (1.f + expf(-g0));
    float sf = 1.f / (1.f + expf(-g1));
    float tg = tanhf(g2);
    float so = 1.f / (1.f + expf(-g3));
    float c = sf * cbuf[b * 256 + k] + si * tg;
    cbuf[b * 256 + k] = c;
    float h = so * tanhf(c);
    hout[b * 256 + k] = h;
    cat[(size_t)(t * 16 + b) * H3 + k] = h;
}

// ---------------- attention probs + coverage + cov_loss (16 WGs, one per b) ----------------
__global__ __launch_bounds__(256) void k_att_step(
    const float* __restrict__ h, const float* __restrict__ cov_in, float* __restrict__ cov_out,
    const float* __restrict__ vWh, const float* __restrict__ vWs, const float* __restrict__ vWc,
    const float* __restrict__ c0p, float* __restrict__ attn, float* __restrict__ covloss) {
    __shared__ float red[256];
    __shared__ float vswc[16];
    __shared__ float sm[400];
    int tid = threadIdx.x;
    int b = blockIdx.x;
    // vswc[b2] = vWs.h[b2] + vWc.cov_in[b2]  (computed redundantly per WG; trivial cost)
    int b2 = tid >> 4, seg = tid & 15;
    float p = 0.f;
    for (int j = seg; j < 256; j += 16) p += vWs[j] * h[b2 * 256 + j];
    for (int l = seg; l < 400; l += 16) p += vWc[l] * cov_in[b2 * 400 + l];
    red[tid] = p;
    __syncthreads();
    for (int s = 8; s > 0; s >>= 1) {
        if (seg < s) red[tid] += red[tid + s];
        __syncthreads();
    }
    if (seg == 0) vswc[b2] = red[tid];
    __syncthreads();
    float c0 = c0p[0];
    float lmax = -1e30f;
    for (int l = tid; l < 400; l += 256) {
        float lg = vWh[b * 400 + l] + vswc[(b * 400 + l) & 15] + c0;  // faithful .repeat bug
        sm[l] = lg;
        lmax = fmaxf(lmax, lg);
    }
    red[tid] = lmax;
    __syncthreads();
    for (int s = 128; s > 0; s >>= 1) {
        if (tid < s) red[tid] = fmaxf(red[tid], red[tid + s]);
        __syncthreads();
    }
    float m = red[0];
    __syncthreads();
    float lsum = 0.f;
    for (int l = tid; l < 400; l += 256) {
        float e = expf(sm[l] - m);
        sm[l] = e;
        lsum += e;
    }
    red[tid] = lsum;
    __syncthreads();
    for (int s = 128; s > 0; s >>= 1) {
        if (tid < s) red[tid] += red[tid + s];
        __syncthreads();
    }
    float inv = 1.f / red[0];
    __syncthreads();
    float cl = 0.f;
    for (int l = tid; l < 400; l += 256) {
        float a = sm[l] * inv;
        attn[b * 400 + l] = a;
        float cv = cov_in[b * 400 + l];
        cl += fminf(a, cv);
        cov_out[b * 400 + l] = cv + a;
    }
    red[tid] = cl;
    __syncthreads();
    for (int s = 128; s > 0; s >>= 1) {
        if (tid < s) red[tid] += red[tid + s];
        __syncthreads();
    }
    if (tid == 0) atomicAdd(covloss, red[0]);
}

// ---------------- context = attn . encoded; writes cat_all[.., 256:768] (128 WGs) ----------------
__global__ __launch_bounds__(256) void k_ctx_step(
    const float* __restrict__ attn, const float* __restrict__ enc, float* __restrict__ cat, int t) {
    int bx = blockIdx.x;
    int b = bx >> 3, s = bx & 7;
    int tid = threadIdx.x;
    int j = (s << 6) + (tid & 63);
    int lq = tid >> 6;
    float acc = 0.f;
    for (int l = lq; l < 400; l += 4)
        acc += attn[b * 400 + l] * enc[((size_t)b * LL + l) * H2 + j];
    __shared__ float red[256];
    red[tid] = acc;
    __syncthreads();
    if (lq == 0) {
        float v = red[tid] + red[tid + 64] + red[tid + 128] + red[tid + 192];
        cat[(size_t)(t * 16 + b) * H3 + 256 + j] = v;
    }
}

// ---------------- fp32 -> bf16 convert ----------------
__global__ void k_cvt_bf16(const float* __restrict__ src, __hip_bfloat16* __restrict__ dst,
                           size_t n) {
    size_t stride = (size_t)gridDim.x * blockDim.x;
    for (size_t i = (size_t)blockIdx.x * blockDim.x + threadIdx.x; i < n; i += stride)
        dst[i] = __float2bfloat16(src[i]);
}

// ---------------- bf16 MFMA GEMM: logits[1584,50000] = z @ V2w.T + V2_b, scattered to d_out ----
__global__ __launch_bounds__(256) void k_gemm_v2(
    const short* __restrict__ Abf, const short* __restrict__ Bbf, const float* __restrict__ bias,
    float* __restrict__ out) {
    __shared__ short As[64 * 40];
    __shared__ short Bs[64 * 40];
    int tid = threadIdx.x;
    int m0 = blockIdx.y * 64, n0 = blockIdx.x * 64;
    int wv = tid >> 6, lane = tid & 63;
    int lrow = tid >> 2, lk = (tid & 3) << 3;
    int lm = lane & 15, lkc = (lane >> 4) << 3;
    f32x4_t zero = {0.f, 0.f, 0.f, 0.f};
    f32x4_t acc[4] = {zero, zero, zero, zero};
    for (int k0 = 0; k0 < H3; k0 += 32) {
        uint4 aval = {0, 0, 0, 0}, bval = {0, 0, 0, 0};
        int mr = m0 + lrow;
        if (mr < 1584) aval = *(const uint4*)(Abf + (size_t)mr * H3 + k0 + lk);
        int nr = n0 + lrow;
        if (nr < VV) bval = *(const uint4*)(Bbf + (size_t)nr * H3 + k0 + lk);
        __syncthreads();
        *(uint4*)(As + lrow * 40 + lk) = aval;
        *(uint4*)(Bs + lrow * 40 + lk) = bval;
        __syncthreads();
        bf16x8_t af = *(const bf16x8_t*)(As + (wv * 16 + lm) * 40 + lkc);
#pragma unroll
        for (int j = 0; j < 4; ++j) {
            bf16x8_t bf = *(const bf16x8_t*)(Bs + (j * 16 + lm) * 40 + lkc);
            acc[j] = __builtin_amdgcn_mfma_f32_16x16x32_bf16(af, bf, acc[j], 0, 0, 0);
        }
    }
    int mbase = m0 + wv * 16 + ((lane >> 4) << 2);
#pragma unroll
    for (int j = 0; j < 4; ++j) {
        int n = n0 + j * 16 + lm;
        if (n >= VV) continue;
        float bb = bias[n];
#pragma unroll
        for (int r2 = 0; r2 < 4; ++r2) {
            int m = mbase + r2;
            if (m < 1584) {
                // row m = t*16+b -> out[b][t][n]
                size_t o = (size_t)(m & 15) * (TD * (size_t)VV) + (size_t)(m >> 4) * VV + n;
                out[o] = acc[j][r2] + bb;
            }
        }
    }
}

// ---------------- row softmax over V=50000, in place on d_out ----------------
__global__ __launch_bounds__(256) void k_softmax(float* __restrict__ out) {
    float* row = out + (size_t)blockIdx.x * VV;
    int tid = threadIdx.x;
    float m = -1e30f, s = 0.f;
    for (int i = tid; i < VV; i += 256) {
        float x = row[i];
        if (x > m) {
            s = s * expf(m - x) + 1.f;
            m = x;
        } else {
            s += expf(x - m);
        }
    }
    __shared__ float rm[256], rs[256];
    rm[tid] = m;
    rs[tid] = s;
    __syncthreads();
    for (int st = 128; st > 0; st >>= 1) {
        if (tid < st) {
            float m2 = rm[tid + st], s2 = rs[tid + st];
            float M = fmaxf(rm[tid], m2);
            rs[tid] = rs[tid] * expf(rm[tid] - M) + s2 * expf(m2 - M);
            rm[tid] = M;
        }
        __syncthreads();
    }
    float Mf = rm[0], inv = 1.f / rs[0];
    for (int i = tid; i < VV; i += 256) row[i] = expf(row[i] - Mf) * inv;
}

__global__ void k_covout(float* __restrict__ out, const float* __restrict__ cvl) {
    out[(size_t)BB * TD * VV] = cvl[0];
}

extern "C" void kernel_launch(void* const* d_in, const int* in_sizes, int n_in,
                              void* d_out, int out_size, void* d_ws, size_t ws_size,
                              hipStream_t stream) {
    const int* inputs = (const int*)d_in[0];
    const int* target = (const int*)d_in[1];
    const float* embed = (const float*)d_in[2];
    const float* Wih_f = (const float*)d_in[3];
    const float* Whh_f = (const float*)d_in[4];
    const float* b_f = (const float*)d_in[5];
    const float* Wih_b = (const float*)d_in[6];
    const float* Whh_b = (const float*)d_in[7];
    const float* b_b = (const float*)d_in[8];
    const float* Wih_d = (const float*)d_in[9];
    const float* Whh_d = (const float*)d_in[10];
    const float* b_d = (const float*)d_in[11];
    const float* Wh_w = (const float*)d_in[12];
    const float* Wh_b = (const float*)d_in[13];
    const float* Ws_w = (const float*)d_in[14];
    const float* Ws_b = (const float*)d_in[15];
    const float* Wc_w = (const float*)d_in[16];
    const float* Wc_b = (const float*)d_in[17];
    const float* v_w = (const float*)d_in[18];
    const float* v_b = (const float*)d_in[19];
    const float* V1_w = (const float*)d_in[20];
    const float* V1_b = (const float*)d_in[21];
    const float* V2_w = (const float*)d_in[22];
    const float* V2_b = (const float*)d_in[23];
    float* out = (float*)d_out;
    float* wsf = (float*)d_ws;

    float* Xf = wsf + OFF_XF;
    float* Xb = wsf + OFF_XB;
    float* Xd = wsf + OFF_XD;
    float* enc = wsf + OFF_ENC;
    float* cat = wsf + OFF_CAT;
    float* zall = wsf + OFF_ZALL;
    __hip_bfloat16* zbf = (__hip_bfloat16*)(wsf + OFF_ZBF);
    float* vWh = wsf + OFF_VWH;
    float* vWs = wsf + OFF_VWS;
    float* vWc = wsf + OFF_VWC;
    float* vWhw = wsf + OFF_VWHW;
    float* c0 = wsf + OFF_C0;
    float* hf0 = wsf + OFF_HF0;
    float* hf1 = wsf + OFF_HF1;
    float* hb0 = wsf + OFF_HB0;
    float* hb1 = wsf + OFF_HB1;
    float* hd0 = wsf + OFF_HD0;
    float* hd1 = wsf + OFF_HD1;
    float* cf = wsf + OFF_CF;
    float* cb = wsf + OFF_CB;
    float* cd = wsf + OFF_CD;
    float* covA = wsf + OFF_COVA;
    float* covB = wsf + OFF_COVB;
    float* cvl = wsf + OFF_CVL;
    float* attn = wsf + OFF_ATTN;
    __hip_bfloat16* v2bf = (__hip_bfloat16*)(wsf + OFF_V2BF);

    dim3 blk(256);

    k_init<<<200, 256, 0, stream>>>(wsf + OFF_STATE, (int)ZERO_N);
    k_precomp<<<1, 256, 0, stream>>>(v_w, Ws_w, Wc_w, Wh_w, Wh_b, Ws_b, Wc_b, v_b, vWs, vWc,
                                     vWhw, c0);
    // batched input projections (gather-GEMMs from embed)
    k_gemm_f32<<<dim3(16, 100), blk, 0, stream>>>(nullptr, embed, inputs, LL, Wih_f, b_f, Xf,
                                                  6400, G4, EE);
    k_gemm_f32<<<dim3(16, 100), blk, 0, stream>>>(nullptr, embed, inputs, LL, Wih_b, b_b, Xb,
                                                  6400, G4, EE);
    k_gemm_f32<<<dim3(16, 25), blk, 0, stream>>>(nullptr, embed, target, 100, Wih_d, b_d, Xd,
                                                 1584, G4, EE);
    // encoder recurrence: 400 steps, fwd+bwd fused per launch
    for (int t = 0; t < LL; ++t) {
        const float* hinf = (t & 1) ? hf1 : hf0;
        float* houtf = (t & 1) ? hf0 : hf1;
        const float* hinb = (t & 1) ? hb1 : hb0;
        float* houtb = (t & 1) ? hb0 : hb1;
        k_enc_step<<<32, 256, 0, stream>>>(Xf, Xb, Whh_f, Whh_b, hinf, hinb, houtf, houtb, cf,
                                           cb, enc, t);
    }
    k_vwh<<<25, 256, 0, stream>>>(enc, vWhw, vWh);
    // decoder recurrence: 99 steps x (LSTM, attention, context)
    for (int t = 0; t < TD; ++t) {
        const float* hin = (t & 1) ? hd1 : hd0;
        float* hout = (t & 1) ? hd0 : hd1;
        const float* cin = (t & 1) ? covB : covA;
        float* cout = (t & 1) ? covA : covB;
        k_dec_step<<<16, 256, 0, stream>>>(Xd, Whh_d, hin, hout, cd, cat, t);
        k_att_step<<<16, 256, 0, stream>>>(hout, cin, cout, vWh, vWs, vWc, c0, attn, cvl);
        k_ctx_step<<<128, 256, 0, stream>>>(attn, enc, cat, t);
    }
    // z = cat @ V1.T + V1_b  (batched over all 99 steps)
    k_gemm_f32<<<dim3(12, 25), blk, 0, stream>>>(cat, nullptr, nullptr, 0, V1_w, V1_b, zall,
                                                 1584, H3, H3);
    k_cvt_bf16<<<2048, 256, 0, stream>>>(zall, zbf, (size_t)1584 * H3);
    k_cvt_bf16<<<4096, 256, 0, stream>>>(V2_w, v2bf, (size_t)VV * H3);
    // logits = z @ V2.T + V2_b (bf16 MFMA), written to final [b][t][v] positions
    k_gemm_v2<<<dim3(782, 25), blk, 0, stream>>>((const short*)zbf, (const short*)v2bf, V2_b,
                                                 out);
    k_softmax<<<1584, 256, 0, stream>>>(out);
    k_covout<<<1, 1, 0, stream>>>(out, cvl);
}

// Round 2
// 4007.493 us; speedup vs baseline: 2.9084x; 2.9084x over previous
//
#include <hip/hip_runtime.h>
#include <hip/hip_bf16.h>
#include <hip/hip_fp16.h>

// BiLSTM encoder (L=400) + coverage-attention LSTM decoder (T-1=99) + V=50000 softmax.
// B=16, E=128, H=256, 4H=1024, 2H=512, 3H=768.
//
// Round-2 structure:
//  - encoder: ONE persistent kernel, 32 WGs (2 dir x 16 k-slices). Whh held as
//    register-resident split-bf16 MFMA B-fragments; per-step grid sync via
//    monotonic agent-scope atomic counter (+ __threadfence both sides).
//  - decoder: ONE persistent kernel, 16 WGs, ONE barrier/step. The LSTM carry
//    never consumes context, so context is hoisted out of the loop entirely.
//  - context for all 99 steps: batched f16 MFMA GEMM (attn[99,400] @ enc[400,512] per b).
//  - all dense math on MFMA. Recurrence matmuls use split-bf16 (hi+lo, 3 MFMA)
//    for ~fp32 accuracy; V1/V2 single-bf16 (proven in round 1).
//  - encT (f16, transposed enc) aliases dead Xf region.

#define BB 16
#define LL 400
#define TD 99
#define G4 1024
#define H2 512
#define H3 768
#define VV 50000

typedef __attribute__((ext_vector_type(8))) short bf16x8_t;
typedef __attribute__((ext_vector_type(8))) _Float16 f16x8_t;
typedef __attribute__((ext_vector_type(4))) float f32x4_t;
typedef unsigned short ushort_t;

static constexpr size_t OFF_XF   = 0;            // 6,553,600  (aliased by encT f16 after encoder)
static constexpr size_t OFF_XB   = 6553600;      // 6,553,600
static constexpr size_t OFF_XD   = 13107200;     // 1,622,016
static constexpr size_t OFF_ENC  = 14729216;     // 3,276,800
static constexpr size_t OFF_CAT  = 18006016;     // 1,216,512
static constexpr size_t OFF_ZBF  = 19222528;     // 786,432 floats = ushort[2048*768]
static constexpr size_t OFF_ATTN = 20008960;     // 372,736 floats = half[16*112*416]
static constexpr size_t OFF_VWH  = 20381696;     // 6400
static constexpr size_t OFF_VWS  = 20388096;     // 256
static constexpr size_t OFF_VWC  = 20388352;     // 512
static constexpr size_t OFF_VWHW = 20388864;     // 512
static constexpr size_t OFF_C0   = 20389376;     // 16
static constexpr size_t OFF_HENC = 20389392;     // 16,384 floats = ushort[2][2][2][4096]
static constexpr size_t OFF_HDEC = 20405776;     // 8,192 floats = ushort[2][2][4096]
static constexpr size_t OFF_PPUB = 20413968;     // 512
static constexpr size_t OFF_QPUB = 20414480;     // 32
static constexpr size_t OFF_CNT  = 20414512;     // 64 (u32 counters: +0 enc dir0, +16 enc dir1, +32 dec)
static constexpr size_t OFF_CVL  = 20414576;     // 16
static constexpr size_t OFF_END  = 20414592;     // ~81.7 MB
static constexpr size_t ZERO_N   = OFF_END - OFF_HENC;  // 25,200

__device__ __forceinline__ ushort_t f2bf(float x) {
    unsigned u = __float_as_uint(x);
    unsigned r = u + 0x7FFFu + ((u >> 16) & 1u);
    return (ushort_t)(r >> 16);
}
__device__ __forceinline__ float bf2f(ushort_t h) {
    return __uint_as_float(((unsigned)h) << 16);
}
__device__ __forceinline__ float wred_sum(float v) {
#pragma unroll
    for (int o = 32; o; o >>= 1) v += __shfl_xor(v, o);
    return v;
}
__device__ __forceinline__ float wred_max(float v) {
#pragma unroll
    for (int o = 32; o; o >>= 1) v = fmaxf(v, __shfl_xor(v, o));
    return v;
}
__device__ __forceinline__ float sigf(float x) { return 1.f / (1.f + expf(-x)); }

// ---------------- init: zero state region ----------------
__global__ void k_init(float* __restrict__ p, int n) {
    for (int i = blockIdx.x * blockDim.x + threadIdx.x; i < n; i += gridDim.x * blockDim.x)
        p[i] = 0.0f;
}

// ---------------- precompute v-folded attention vectors ----------------
__global__ void k_precomp(const float* __restrict__ v, const float* __restrict__ Ws_w,
                          const float* __restrict__ Wc_w, const float* __restrict__ Wh_w,
                          const float* __restrict__ Wh_b, const float* __restrict__ Ws_b,
                          const float* __restrict__ Wc_b, const float* __restrict__ v_b,
                          float* __restrict__ vWs, float* __restrict__ vWc,
                          float* __restrict__ vWhw, float* __restrict__ c0) {
    int tid = threadIdx.x;
    {
        float a = 0.f;
        for (int j = 0; j < 256; ++j) a += v[j] * Ws_w[j * 256 + tid];
        vWs[tid] = a;
    }
    for (int k = tid; k < 400; k += 256) {
        float a = 0.f;
        for (int j = 0; j < 256; ++j) a += v[j] * Wc_w[j * 400 + k];
        vWc[k] = a;
    }
    for (int k = tid; k < 512; k += 256) {
        float a = 0.f;
        for (int j = 0; j < 256; ++j) a += v[j] * Wh_w[j * 512 + k];
        vWhw[k] = a;
    }
    if (tid == 0) {
        float a = 0.f;
        for (int j = 0; j < 256; ++j) a += v[j] * (Wh_b[j] + Ws_b[j] + Wc_b[j]);
        c0[0] = a + v_b[0];
    }
}

// ---------------- gather x-projection GEMM (split-bf16, 3 MFMA) ----------------
// C[M,1024] = embed[tok(m)] @ Wih.T + bias ; tok(m) = toks[(m&15)*S + (m>>4)]
__global__ __launch_bounds__(256) void k_xproj(
    const float* __restrict__ emb, const int* __restrict__ toks, int tokStride,
    const float* __restrict__ Wih, const float* __restrict__ bias,
    float* __restrict__ C, int M) {
    __shared__ __attribute__((aligned(16))) ushort_t Ah[64 * 32], Al[64 * 32];
    __shared__ __attribute__((aligned(16))) ushort_t Bh[64 * 32], Bl[64 * 32];
    int tid = threadIdx.x;
    int m0 = blockIdx.y * 64, n0 = blockIdx.x * 64;
    int lrow = tid >> 2, lc = (tid & 3) * 8;
    int g = tid >> 6, lane = tid & 63, lm = lane & 15, quad = lane >> 4;
    f32x4_t acc[4];
#pragma unroll
    for (int i = 0; i < 4; ++i) acc[i] = (f32x4_t){0.f, 0.f, 0.f, 0.f};
    int mr = m0 + lrow;
    int l = mr >> 4, bb2 = mr & 15;
    int tok = (mr < M) ? toks[bb2 * tokStride + l] : 0;
    const float* arow = emb + (size_t)tok * 128;
    const float* brow = Wih + (size_t)(n0 + lrow) * 128;
    for (int k0 = 0; k0 < 128; k0 += 32) {
        float av[8], bv[8];
        *(float4*)(av) = *(const float4*)(arow + k0 + lc);
        *(float4*)(av + 4) = *(const float4*)(arow + k0 + lc + 4);
        *(float4*)(bv) = *(const float4*)(brow + k0 + lc);
        *(float4*)(bv + 4) = *(const float4*)(brow + k0 + lc + 4);
        __syncthreads();
#pragma unroll
        for (int j = 0; j < 8; ++j) {
            ushort_t h = f2bf(av[j]);
            Ah[lrow * 32 + lc + j] = h;
            Al[lrow * 32 + lc + j] = f2bf(av[j] - bf2f(h));
            ushort_t h2 = f2bf(bv[j]);
            Bh[lrow * 32 + lc + j] = h2;
            Bl[lrow * 32 + lc + j] = f2bf(bv[j] - bf2f(h2));
        }
        __syncthreads();
        bf16x8_t ah = *(const bf16x8_t*)(Ah + (g * 16 + lm) * 32 + quad * 8);
        bf16x8_t al = *(const bf16x8_t*)(Al + (g * 16 + lm) * 32 + quad * 8);
#pragma unroll
        for (int ns = 0; ns < 4; ++ns) {
            bf16x8_t bh = *(const bf16x8_t*)(Bh + (ns * 16 + lm) * 32 + quad * 8);
            bf16x8_t bl = *(const bf16x8_t*)(Bl + (ns * 16 + lm) * 32 + quad * 8);
            acc[ns] = __builtin_amdgcn_mfma_f32_16x16x32_bf16(ah, bh, acc[ns], 0, 0, 0);
            acc[ns] = __builtin_amdgcn_mfma_f32_16x16x32_bf16(ah, bl, acc[ns], 0, 0, 0);
            acc[ns] = __builtin_amdgcn_mfma_f32_16x16x32_bf16(al, bh, acc[ns], 0, 0, 0);
        }
    }
#pragma unroll
    for (int ns = 0; ns < 4; ++ns) {
        int n = n0 + ns * 16 + lm;
        float bb = bias[n];
#pragma unroll
        for (int r2 = 0; r2 < 4; ++r2) {
            int mm = m0 + g * 16 + quad * 4 + r2;
            if (mm < M) C[(size_t)mm * 1024 + n] = acc[ns][r2] + bb;
        }
    }
}

// ---------------- persistent encoder: 32 WGs = 2 dirs x 16 k-slices ----------------
__global__ __launch_bounds__(256) void k_enc_pers(
    const float* __restrict__ Xf, const float* __restrict__ Xb,
    const float* __restrict__ Whh_f, const float* __restrict__ Whh_b,
    ushort_t* __restrict__ hbuf, unsigned* __restrict__ cnts, float* __restrict__ enc) {
    __shared__ float pre[1024];
    int bx = blockIdx.x;
    int q = bx >> 3, r = bx & 7;
    int dir = r >> 2;
    int w = q * 4 + (r & 3);            // XCD-split: each dir lives on 4 XCDs
    const float* Whh = dir ? Whh_b : Whh_f;
    const float* X = dir ? Xb : Xf;
    unsigned* cnt = cnts + dir * 16;
    ushort_t* hb = hbuf + dir * 16384;  // [par][plane][4096]
    int tid = threadIdx.x;
    int g = tid >> 6, lane = tid & 63, lm = lane & 15, quad = lane >> 4;
    int gbase = 256 * g + 16 * w;
    bf16x8_t Bh[8], Bl[8];
    {
        const float* wr = Whh + (size_t)(gbase + lm) * 256;
#pragma unroll
        for (int kk = 0; kk < 8; ++kk) {
            union { bf16x8_t v; ushort_t u[8]; } hh, ll;
#pragma unroll
            for (int j = 0; j < 8; ++j) {
                float x = wr[kk * 32 + quad * 8 + j];
                ushort_t hi = f2bf(x);
                hh.u[j] = hi;
                ll.u[j] = f2bf(x - bf2f(hi));
            }
            Bh[kk] = hh.v;
            Bl[kk] = ll.v;
        }
    }
    int m = tid >> 4, kk16 = tid & 15;
    int k = w * 16 + kk16;
    float c = 0.f;
    int l0 = dir ? 399 : 0;
    const float* Xr0 = X + (size_t)(l0 * 16 + m) * 1024;
    float x0 = Xr0[k], x1 = Xr0[256 + k], x2 = Xr0[512 + k], x3 = Xr0[768 + k];
    for (int t = 0; t < 400; ++t) {
        int par = t & 1;
        const ushort_t* hin = hb + par * 8192;
        f32x4_t acc = (f32x4_t){0.f, 0.f, 0.f, 0.f};
#pragma unroll
        for (int kk = 0; kk < 8; ++kk) {
            bf16x8_t ah = *(const bf16x8_t*)(hin + lm * 256 + kk * 32 + quad * 8);
            bf16x8_t al = *(const bf16x8_t*)(hin + 4096 + lm * 256 + kk * 32 + quad * 8);
            acc = __builtin_amdgcn_mfma_f32_16x16x32_bf16(ah, Bh[kk], acc, 0, 0, 0);
            acc = __builtin_amdgcn_mfma_f32_16x16x32_bf16(ah, Bl[kk], acc, 0, 0, 0);
            acc = __builtin_amdgcn_mfma_f32_16x16x32_bf16(al, Bh[kk], acc, 0, 0, 0);
        }
#pragma unroll
        for (int r2 = 0; r2 < 4; ++r2) pre[g * 256 + (quad * 4 + r2) * 16 + lm] = acc[r2];
        __syncthreads();
        float gi = pre[tid] + x0;
        float gf = pre[256 + tid] + x1;
        float gg = pre[512 + tid] + x2;
        float go = pre[768 + tid] + x3;
        int l = dir ? (399 - t) : t;
        if (t < 399) {  // prefetch next step's x
            int ln = dir ? (398 - t) : (t + 1);
            const float* Xr = X + (size_t)(ln * 16 + m) * 1024;
            x0 = Xr[k]; x1 = Xr[256 + k]; x2 = Xr[512 + k]; x3 = Xr[768 + k];
        }
        c = sigf(gf) * c + sigf(gi) * tanhf(gg);
        float h = sigf(go) * tanhf(c);
        enc[((size_t)m * 400 + l) * 512 + dir * 256 + k] = h;
        ushort_t hhi = f2bf(h);
        ushort_t hlo = f2bf(h - bf2f(hhi));
        ushort_t* ho = hb + (1 - par) * 8192;
        ho[m * 256 + k] = hhi;
        ho[4096 + m * 256 + k] = hlo;
        __syncthreads();   // drains vmcnt: all WG stores complete
        if (tid == 0) {
            __threadfence();  // release (agent): write back to coherence point
            __hip_atomic_fetch_add(cnt, 1u, __ATOMIC_RELAXED, __HIP_MEMORY_SCOPE_AGENT);
            unsigned tgt = (unsigned)(t + 1) * 16u;
            while (__hip_atomic_load(cnt, __ATOMIC_RELAXED, __HIP_MEMORY_SCOPE_AGENT) < tgt)
                __builtin_amdgcn_s_sleep(2);
            __threadfence();  // acquire: invalidate stale caches
        }
        __syncthreads();
    }
}

// ---------------- vWh[b*L+l] = vWhw . enc[b,l,:] ----------------
__global__ void k_vwh(const float* __restrict__ enc, const float* __restrict__ vWhw,
                      float* __restrict__ vWh) {
    int rr = blockIdx.x * 256 + threadIdx.x;
    const float* row = enc + (size_t)rr * H2;
    float acc = 0.f;
#pragma unroll 4
    for (int k = 0; k < H2; k += 4) {
        float4 e = *(const float4*)(row + k);
        float4 wv = *(const float4*)(vWhw + k);
        acc += e.x * wv.x + e.y * wv.y + e.z * wv.z + e.w * wv.w;
    }
    vWh[rr] = acc;
}

// ---------------- transpose enc -> encT f16 [b][j][l(416, zero-padded)] ----------------
__global__ __launch_bounds__(256) void k_transpose(const float* __restrict__ enc,
                                                   __half* __restrict__ encT) {
    __shared__ float tb[64][65];
    int lt = blockIdx.x, jt = blockIdx.y, b = blockIdx.z;
    int l0 = lt * 64, j0 = jt * 64;
    int tid = threadIdx.x;
    for (int i = tid; i < 4096; i += 256) {
        int li = i >> 6, jj = i & 63;
        int l = l0 + li;
        tb[jj][li] = (l < 400) ? enc[((size_t)b * 400 + l) * 512 + j0 + jj] : 0.f;
    }
    __syncthreads();
    for (int i = tid; i < 4096; i += 256) {
        int jj = i >> 6, li = i & 63;
        int l = l0 + li;
        if (l < 416) encT[((size_t)b * 512 + j0 + jj) * 416 + l] = __float2half(tb[jj][li]);
    }
}

// ---------------- persistent decoder: 16 WGs (k-slice for LSTM, batch for attention) ----
__global__ __launch_bounds__(256) void k_dec_pers(
    const float* __restrict__ Xd, const float* __restrict__ Whh_d,
    ushort_t* __restrict__ hbuf, unsigned* __restrict__ cnt,
    const float* __restrict__ vWh, const float* __restrict__ vWs,
    const float* __restrict__ vWc, const float* __restrict__ c0g,
    float* __restrict__ p_pub, float* __restrict__ q_pub, float* __restrict__ cat,
    __half* __restrict__ attn_g, float* __restrict__ cvl) {
    __shared__ float pre[1024];
    __shared__ float covL[400];
    __shared__ float vred[256];
    __shared__ float psh[256];
    __shared__ float vswcS[16];
    __shared__ float rr[8];
    int w = blockIdx.x;
    int b = w;
    int tid = threadIdx.x;
    int g = tid >> 6, lane = tid & 63, lm = lane & 15, quad = lane >> 4;
    int gbase = 256 * g + 16 * w;
    bf16x8_t Bh[8], Bl[8];
    {
        const float* wr = Whh_d + (size_t)(gbase + lm) * 256;
#pragma unroll
        for (int kk = 0; kk < 8; ++kk) {
            union { bf16x8_t v; ushort_t u[8]; } hh, ll;
#pragma unroll
            for (int j = 0; j < 8; ++j) {
                float x = wr[kk * 32 + quad * 8 + j];
                ushort_t hi = f2bf(x);
                hh.u[j] = hi;
                ll.u[j] = f2bf(x - bf2f(hi));
            }
            Bh[kk] = hh.v;
            Bl[kk] = ll.v;
        }
    }
    int m = tid >> 4, kk16 = tid & 15;
    int k = w * 16 + kk16;
    float c = 0.f, cl_acc = 0.f;
    for (int i = tid; i < 400; i += 256) covL[i] = 0.f;
    float c0v = c0g[0];
    float vwsk = vWs[k];
    const float* Xr0 = Xd + (size_t)m * 1024;
    float x0 = Xr0[k], x1 = Xr0[256 + k], x2 = Xr0[512 + k], x3 = Xr0[768 + k];
    __syncthreads();
    for (int t = 0; t < TD; ++t) {
        int par = t & 1;
        // ---- LSTM MFMA ----
        const ushort_t* hin = hbuf + par * 8192;
        f32x4_t acc = (f32x4_t){0.f, 0.f, 0.f, 0.f};
#pragma unroll
        for (int kk = 0; kk < 8; ++kk) {
            bf16x8_t ah = *(const bf16x8_t*)(hin + lm * 256 + kk * 32 + quad * 8);
            bf16x8_t al = *(const bf16x8_t*)(hin + 4096 + lm * 256 + kk * 32 + quad * 8);
            acc = __builtin_amdgcn_mfma_f32_16x16x32_bf16(ah, Bh[kk], acc, 0, 0, 0);
            acc = __builtin_amdgcn_mfma_f32_16x16x32_bf16(ah, Bl[kk], acc, 0, 0, 0);
            acc = __builtin_amdgcn_mfma_f32_16x16x32_bf16(al, Bh[kk], acc, 0, 0, 0);
        }
#pragma unroll
        for (int r2 = 0; r2 < 4; ++r2) pre[g * 256 + (quad * 4 + r2) * 16 + lm] = acc[r2];
        // ---- q = vWc . cov (cov from previous step) ----
        float qv = 0.f;
        for (int i = tid; i < 400; i += 256) qv += vWc[i] * covL[i];
        qv = wred_sum(qv);
        if (lane == 0) rr[g] = qv;
        __syncthreads();
        // ---- activations ----
        float gi = pre[tid] + x0;
        float gf = pre[256 + tid] + x1;
        float gg = pre[512 + tid] + x2;
        float go = pre[768 + tid] + x3;
        if (t < TD - 1) {
            const float* Xr = Xd + (size_t)((t + 1) * 16 + m) * 1024;
            x0 = Xr[k]; x1 = Xr[256 + k]; x2 = Xr[512 + k]; x3 = Xr[768 + k];
        }
        c = sigf(gf) * c + sigf(gi) * tanhf(gg);
        float h = sigf(go) * tanhf(c);
        cat[((size_t)t * 16 + m) * 768 + k] = h;
        ushort_t hhi = f2bf(h);
        ushort_t hlo = f2bf(h - bf2f(hhi));
        ushort_t* ho = hbuf + (1 - par) * 8192;
        ho[m * 256 + k] = hhi;
        ho[4096 + m * 256 + k] = hlo;
        psh[tid] = vwsk * h;
        if (tid == 0) q_pub[par * 16 + b] = rr[0] + rr[1] + rr[2] + rr[3];
        __syncthreads();
        if (tid < 16) {
            float s = 0.f;
#pragma unroll
            for (int j = 0; j < 16; ++j) s += psh[tid * 16 + j];
            p_pub[par * 256 + w * 16 + tid] = s;
        }
        __syncthreads();   // drains vmcnt for all waves before fence
        // ---- grid barrier ----
        if (tid == 0) {
            __threadfence();
            __hip_atomic_fetch_add(cnt, 1u, __ATOMIC_RELAXED, __HIP_MEMORY_SCOPE_AGENT);
            unsigned tgt = (unsigned)(t + 1) * 16u;
            while (__hip_atomic_load(cnt, __ATOMIC_RELAXED, __HIP_MEMORY_SCOPE_AGENT) < tgt)
                __builtin_amdgcn_s_sleep(2);
            __threadfence();
        }
        __syncthreads();
        // ---- attention (WG = batch b) ----
        vred[tid] = p_pub[par * 256 + tid];
        __syncthreads();
        if (tid < 128) vred[tid] += vred[tid + 128];
        __syncthreads();
        if (tid < 64) vred[tid] += vred[tid + 64];
        __syncthreads();
        if (tid < 32) vred[tid] += vred[tid + 32];
        __syncthreads();
        if (tid < 16) vswcS[tid] = vred[tid] + vred[tid + 16] + q_pub[par * 16 + tid];
        __syncthreads();
        bool has2 = tid < 144;
        float vs = vswcS[tid & 15] + c0v;  // (b*400+l)%16 == l%16 == tid%16 for both l=tid, tid+256
        float lg1 = vWh[b * 400 + tid] + vs;
        float lg2 = has2 ? (vWh[b * 400 + 256 + tid] + vs) : -1e30f;
        float mx = wred_max(fmaxf(lg1, lg2));
        if (lane == 0) rr[g] = mx;
        __syncthreads();
        float M = fmaxf(fmaxf(rr[0], rr[1]), fmaxf(rr[2], rr[3]));
        float e1 = expf(lg1 - M);
        float e2 = has2 ? expf(lg2 - M) : 0.f;
        float sv = wred_sum(e1 + e2);
        if (lane == 0) rr[4 + g] = sv;
        __syncthreads();
        float inv = 1.f / (rr[4] + rr[5] + rr[6] + rr[7]);
        float a1 = e1 * inv, a2 = e2 * inv;
        float cv1 = covL[tid];
        float cl = fminf(a1, cv1);
        covL[tid] = cv1 + a1;
        __half* arow = attn_g + ((size_t)b * 112 + t) * 416;
        arow[tid] = __float2half(a1);
        if (has2) {
            float cv2 = covL[tid + 256];
            cl += fminf(a2, cv2);
            covL[tid + 256] = cv2 + a2;
            arow[256 + tid] = __float2half(a2);
        }
        cl = wred_sum(cl);
        __syncthreads();
        if (lane == 0) rr[g] = cl;
        __syncthreads();
        if (tid == 0) cl_acc += rr[0] + rr[1] + rr[2] + rr[3];
        __syncthreads();   // covL updates visible before next step's q
    }
    if (tid == 0) atomicAdd(cvl, cl_acc);
}

// ---------------- batched context GEMM: cat[t*16+b][256:768] = attn @ enc ----------------
__global__ __launch_bounds__(256) void k_ctx_gemm(const __half* __restrict__ attn_g,
                                                  const __half* __restrict__ encT,
                                                  float* __restrict__ cat) {
    int jt = blockIdx.x, b = blockIdx.y;
    int tid = threadIdx.x, v = tid >> 6, lane = tid & 63, lm = lane & 15, quad = lane >> 4;
    f32x4_t acc[7];
#pragma unroll
    for (int i = 0; i < 7; ++i) acc[i] = (f32x4_t){0.f, 0.f, 0.f, 0.f};
    int j = jt * 64 + v * 16 + lm;
    const _Float16* brow = (const _Float16*)(encT + ((size_t)b * 512 + j) * 416);
    const _Float16* abase = (const _Float16*)(attn_g + (size_t)b * 112 * 416);
    for (int k0 = 0; k0 < 416; k0 += 32) {
        f16x8_t bf = *(const f16x8_t*)(brow + k0 + quad * 8);
#pragma unroll
        for (int mt = 0; mt < 7; ++mt) {
            f16x8_t af = *(const f16x8_t*)(abase + (size_t)(mt * 16 + lm) * 416 + k0 + quad * 8);
            acc[mt] = __builtin_amdgcn_mfma_f32_16x16x32_f16(af, bf, acc[mt], 0, 0, 0);
        }
    }
#pragma unroll
    for (int mt = 0; mt < 7; ++mt)
#pragma unroll
        for (int r2 = 0; r2 < 4; ++r2) {
            int t = mt * 16 + quad * 4 + r2;
            if (t < 99) cat[((size_t)t * 16 + b) * 768 + 256 + j] = acc[mt][r2];
        }
}

// ---------------- V1 GEMM: zbf[2048,768] = bf16(cat @ V1.T + b) ----------------
__global__ __launch_bounds__(256) void k_gemm_v1(const float* __restrict__ A,
                                                 const float* __restrict__ Bw,
                                                 const float* __restrict__ bias,
                                                 ushort_t* __restrict__ Cbf) {
    __shared__ __attribute__((aligned(16))) ushort_t As[64 * 32], Bs[64 * 32];
    int tid = threadIdx.x;
    int m0 = blockIdx.y * 64, n0 = blockIdx.x * 64;
    int lrow = tid >> 2, lc = (tid & 3) * 8;
    int g = tid >> 6, lane = tid & 63, lm = lane & 15, quad = lane >> 4;
    f32x4_t acc[4];
#pragma unroll
    for (int i = 0; i < 4; ++i) acc[i] = (f32x4_t){0.f, 0.f, 0.f, 0.f};
    const float* ap0 = A + (size_t)(m0 + lrow) * 768;
    const float* bp0 = Bw + (size_t)(n0 + lrow) * 768;
    for (int k0 = 0; k0 < 768; k0 += 32) {
        float av[8], bv[8];
        *(float4*)av = *(const float4*)(ap0 + k0 + lc);
        *(float4*)(av + 4) = *(const float4*)(ap0 + k0 + lc + 4);
        *(float4*)bv = *(const float4*)(bp0 + k0 + lc);
        *(float4*)(bv + 4) = *(const float4*)(bp0 + k0 + lc + 4);
        __syncthreads();
#pragma unroll
        for (int jj = 0; jj < 8; ++jj) {
            As[lrow * 32 + lc + jj] = f2bf(av[jj]);
            Bs[lrow * 32 + lc + jj] = f2bf(bv[jj]);
        }
        __syncthreads();
        bf16x8_t ah = *(const bf16x8_t*)(As + (g * 16 + lm) * 32 + quad * 8);
#pragma unroll
        for (int ns = 0; ns < 4; ++ns) {
            bf16x8_t bh = *(const bf16x8_t*)(Bs + (ns * 16 + lm) * 32 + quad * 8);
            acc[ns] = __builtin_amdgcn_mfma_f32_16x16x32_bf16(ah, bh, acc[ns], 0, 0, 0);
        }
    }
#pragma unroll
    for (int ns = 0; ns < 4; ++ns) {
        int n = n0 + ns * 16 + lm;
        float bb = bias[n];
#pragma unroll
        for (int r2 = 0; r2 < 4; ++r2) {
            int mm = m0 + g * 16 + quad * 4 + r2;
            Cbf[(size_t)mm * 768 + n] = f2bf(acc[ns][r2] + bb);
        }
    }
}

// ---------------- V2 GEMM: out[b][t][n] = softmax-input logits (bf16 MFMA) ----------------
// M-tile 512 x N-tile 64; A = zbf (bf16, L2-resident), B = V2_w fp32 staged->bf16.
__global__ __launch_bounds__(256) void k_gemm_v2(const ushort_t* __restrict__ Abf,
                                                 const float* __restrict__ V2w,
                                                 const float* __restrict__ bias,
                                                 float* __restrict__ out) {
    __shared__ __attribute__((aligned(16))) ushort_t As[512 * 32];
    __shared__ __attribute__((aligned(16))) ushort_t Bs[64 * 32];
    int tid = threadIdx.x;
    int n0 = blockIdx.x * 64;
    int m0 = blockIdx.y * 512;
    int v = tid >> 6, lane = tid & 63, lm = lane & 15, quad = lane >> 4;
    int lrow = tid >> 2, lc = (tid & 3) * 8;
    f32x4_t acc[8][4];
#pragma unroll
    for (int i = 0; i < 8; ++i)
#pragma unroll
        for (int jn = 0; jn < 4; ++jn) acc[i][jn] = (f32x4_t){0.f, 0.f, 0.f, 0.f};
    int nr = n0 + lrow;
    for (int k0 = 0; k0 < 768; k0 += 32) {
        __syncthreads();
#pragma unroll
        for (int i = 0; i < 8; ++i) {
            int row = i * 64 + lrow;
            *(uint4*)(As + row * 32 + lc) =
                *(const uint4*)(Abf + (size_t)(m0 + row) * 768 + k0 + lc);
        }
        {
            float bv8[8];
            if (nr < VV) {
                const float* bp = V2w + (size_t)nr * 768 + k0 + lc;
                *(float4*)bv8 = *(const float4*)bp;
                *(float4*)(bv8 + 4) = *(const float4*)(bp + 4);
            } else {
#pragma unroll
                for (int jj = 0; jj < 8; ++jj) bv8[jj] = 0.f;
            }
#pragma unroll
            for (int jj = 0; jj < 8; ++jj) Bs[lrow * 32 + lc + jj] = f2bf(bv8[jj]);
        }
        __syncthreads();
        bf16x8_t bn[4];
#pragma unroll
        for (int ns = 0; ns < 4; ++ns)
            bn[ns] = *(const bf16x8_t*)(Bs + (ns * 16 + lm) * 32 + quad * 8);
#pragma unroll
        for (int ms = 0; ms < 8; ++ms) {
            bf16x8_t ah = *(const bf16x8_t*)(As + (v * 128 + ms * 16 + lm) * 32 + quad * 8);
#pragma unroll
            for (int ns = 0; ns < 4; ++ns)
                acc[ms][ns] = __builtin_amdgcn_mfma_f32_16x16x32_bf16(ah, bn[ns], acc[ms][ns], 0, 0, 0);
        }
    }
#pragma unroll
    for (int ms = 0; ms < 8; ++ms)
#pragma unroll
        for (int ns = 0; ns < 4; ++ns) {
            int n = n0 + ns * 16 + lm;
            if (n >= VV) continue;
            float bb = bias[n];
#pragma unroll
            for (int r2 = 0; r2 < 4; ++r2) {
                int mrow = m0 + v * 128 + ms * 16 + quad * 4 + r2;
                if (mrow < 1584)
                    out[(size_t)(mrow & 15) * (TD * (size_t)VV) + (size_t)(mrow >> 4) * VV + n] =
                        acc[ms][ns][r2] + bb;
            }
        }
}

// ---------------- row softmax over V=50000, in place on d_out ----------------
__global__ __launch_bounds__(256) void k_softmax(float* __restrict__ out) {
    float* row = out + (size_t)blockIdx.x * VV;
    int tid = threadIdx.x;
    float m = -1e30f, s = 0.f;
    for (int i = tid; i < VV; i += 256) {
        float x = row[i];
        if (x > m) {
            s = s * expf(m - x) + 1.f;
            m = x;
        } else {
            s += expf(x - m);
        }
    }
    __shared__ float rm[256], rs[256];
    rm[tid] = m;
    rs[tid] = s;
    __syncthreads();
    for (int st = 128; st > 0; st >>= 1) {
        if (tid < st) {
            float m2 = rm[tid + st], s2 = rs[tid + st];
            float M = fmaxf(rm[tid], m2);
            rs[tid] = rs[tid] * expf(rm[tid] - M) + s2 * expf(m2 - M);
            rm[tid] = M;
        }
        __syncthreads();
    }
    float Mf = rm[0], inv = 1.f / rs[0];
    for (int i = tid; i < VV; i += 256) row[i] = expf(row[i] - Mf) * inv;
}

__global__ void k_covout(float* __restrict__ out, const float* __restrict__ cvl) {
    out[(size_t)BB * TD * VV] = cvl[0];
}

extern "C" void kernel_launch(void* const* d_in, const int* in_sizes, int n_in,
                              void* d_out, int out_size, void* d_ws, size_t ws_size,
                              hipStream_t stream) {
    const int* inputs = (const int*)d_in[0];
    const int* target = (const int*)d_in[1];
    const float* embed = (const float*)d_in[2];
    const float* Wih_f = (const float*)d_in[3];
    const float* Whh_f = (const float*)d_in[4];
    const float* b_f = (const float*)d_in[5];
    const float* Wih_b = (const float*)d_in[6];
    const float* Whh_b = (const float*)d_in[7];
    const float* b_b = (const float*)d_in[8];
    const float* Wih_d = (const float*)d_in[9];
    const float* Whh_d = (const float*)d_in[10];
    const float* b_d = (const float*)d_in[11];
    const float* Wh_w = (const float*)d_in[12];
    const float* Wh_b = (const float*)d_in[13];
    const float* Ws_w = (const float*)d_in[14];
    const float* Ws_b = (const float*)d_in[15];
    const float* Wc_w = (const float*)d_in[16];
    const float* Wc_b = (const float*)d_in[17];
    const float* v_w = (const float*)d_in[18];
    const float* v_b = (const float*)d_in[19];
    const float* V1_w = (const float*)d_in[20];
    const float* V1_b = (const float*)d_in[21];
    const float* V2_w = (const float*)d_in[22];
    const float* V2_b = (const float*)d_in[23];
    float* out = (float*)d_out;
    float* wsf = (float*)d_ws;

    float* Xf = wsf + OFF_XF;
    float* Xb = wsf + OFF_XB;
    float* Xd = wsf + OFF_XD;
    float* enc = wsf + OFF_ENC;
    float* cat = wsf + OFF_CAT;
    ushort_t* zbf = (ushort_t*)(wsf + OFF_ZBF);
    __half* attn_g = (__half*)(wsf + OFF_ATTN);
    __half* encT = (__half*)(wsf + OFF_XF);  // aliases Xf (dead after encoder)
    float* vWh = wsf + OFF_VWH;
    float* vWs = wsf + OFF_VWS;
    float* vWc = wsf + OFF_VWC;
    float* vWhw = wsf + OFF_VWHW;
    float* c0 = wsf + OFF_C0;
    ushort_t* henc = (ushort_t*)(wsf + OFF_HENC);
    ushort_t* hdec = (ushort_t*)(wsf + OFF_HDEC);
    float* p_pub = wsf + OFF_PPUB;
    float* q_pub = wsf + OFF_QPUB;
    unsigned* cnts = (unsigned*)(wsf + OFF_CNT);
    float* cvl = wsf + OFF_CVL;

    dim3 blk(256);
    k_init<<<32, 256, 0, stream>>>(wsf + OFF_HENC, (int)ZERO_N);
    k_precomp<<<1, 256, 0, stream>>>(v_w, Ws_w, Wc_w, Wh_w, Wh_b, Ws_b, Wc_b, v_b, vWs, vWc,
                                     vWhw, c0);
    k_xproj<<<dim3(16, 100), blk, 0, stream>>>(embed, inputs, LL, Wih_f, b_f, Xf, 6400);
    k_xproj<<<dim3(16, 100), blk, 0, stream>>>(embed, inputs, LL, Wih_b, b_b, Xb, 6400);
    k_xproj<<<dim3(16, 25), blk, 0, stream>>>(embed, target, 100, Wih_d, b_d, Xd, 1584);
    k_enc_pers<<<32, blk, 0, stream>>>(Xf, Xb, Whh_f, Whh_b, henc, cnts, enc);
    k_vwh<<<25, 256, 0, stream>>>(enc, vWhw, vWh);
    k_transpose<<<dim3(7, 8, 16), blk, 0, stream>>>(enc, encT);
    k_dec_pers<<<16, blk, 0, stream>>>(Xd, Whh_d, hdec, cnts + 32, vWh, vWs, vWc, c0, p_pub,
                                       q_pub, cat, attn_g, cvl);
    k_ctx_gemm<<<dim3(8, 16), blk, 0, stream>>>(attn_g, encT, cat);
    k_gemm_v1<<<dim3(12, 25), blk, 0, stream>>>(cat, V1_w, V1_b, zbf);
    k_gemm_v2<<<dim3(782, 4), blk, 0, stream>>>(zbf, V2_w, V2_b, out);
    k_softmax<<<1584, 256, 0, stream>>>(out);
    k_covout<<<1, 1, 0, stream>>>(out, cvl);
}